// Round 1
// baseline (8520.493 us; speedup 1.0000x reference)
//
#include <hip/hip_runtime.h>
#include <cstddef>
#include <cstdint>

// Problem constants
// V=32000, H=512, E=512, B=64, S=128, T=48
// Inputs: 0:mr[64,128] i32, 1:ref[64,48] i32, 2:mr_lengths[64] i32, 3:emb[32000,512] f32,
// 4:W_ih_enc[2048,512], 5:W_hh_enc[2048,512], 6:W_ih_dec[2048,512], 7:W_hh_dec[2048,512],
// 8:W_y[32000,1024], 9:W_s[512,1024], 10:W_a1[1,512], 11:W_a2[1,512]
// Output: [64,48,32000] f32 (softmax probs)

// ---------------- sort: order = stable argsort(-lens) ----------------
__global__ __launch_bounds__(64) void k_sort(const int* __restrict__ lens,
                                             int* __restrict__ order,
                                             int* __restrict__ lens_sorted) {
  __shared__ int L[64];
  int i = threadIdx.x;
  L[i] = lens[i];
  __syncthreads();
  int li = L[i];
  int rank = 0;
  for (int j = 0; j < 64; ++j) {
    int lj = L[j];
    if (lj > li || (lj == li && j < i)) ++rank;
  }
  order[rank] = i;
  lens_sorted[rank] = li;
}

// ---------------- token index per encoder-GEMM row ----------------
__global__ __launch_bounds__(256) void k_rowtok(const int* __restrict__ mr,
                                                const int* __restrict__ order,
                                                int* __restrict__ rowtok) {
  int r = blockIdx.x * 256 + threadIdx.x;   // 8192 rows, row = s*64 + i(sorted)
  int s = r >> 6, i = r & 63;
  rowtok[r] = mr[order[i] * 128 + s];
}

// ---------------- xprojT = W_ih_enc @ x_s^T : [2048][8192] ----------------
__global__ __launch_bounds__(256) void k_gemm_xproj(
    const float* __restrict__ A,      // W_ih_enc [2048][512]
    const float* __restrict__ emb,    // [V][512]
    const int* __restrict__ rowtok,   // [8192]
    float* __restrict__ C)            // [2048][8192]
{
  __shared__ float As[32][68];
  __shared__ float Bs[32][68];
  int tid = threadIdx.x;
  int n0 = blockIdx.x * 64;
  int m0 = blockIdx.y * 64;
  int lr = tid >> 2;            // 0..63
  int lk = (tid & 3) * 8;       // 0,8,16,24
  const float* Arow = A + (size_t)(m0 + lr) * 512 + lk;
  const float* Brow = emb + (size_t)rowtok[n0 + lr] * 512 + lk;
  int tx = tid & 15, ty = tid >> 4;
  float acc[4][4] = {};
  for (int k0 = 0; k0 < 512; k0 += 32) {
    float4 a0 = *(const float4*)(Arow + k0);
    float4 a1 = *(const float4*)(Arow + k0 + 4);
    float4 b0 = *(const float4*)(Brow + k0);
    float4 b1 = *(const float4*)(Brow + k0 + 4);
    __syncthreads();
    As[lk+0][lr]=a0.x; As[lk+1][lr]=a0.y; As[lk+2][lr]=a0.z; As[lk+3][lr]=a0.w;
    As[lk+4][lr]=a1.x; As[lk+5][lr]=a1.y; As[lk+6][lr]=a1.z; As[lk+7][lr]=a1.w;
    Bs[lk+0][lr]=b0.x; Bs[lk+1][lr]=b0.y; Bs[lk+2][lr]=b0.z; Bs[lk+3][lr]=b0.w;
    Bs[lk+4][lr]=b1.x; Bs[lk+5][lr]=b1.y; Bs[lk+6][lr]=b1.z; Bs[lk+7][lr]=b1.w;
    __syncthreads();
#pragma unroll
    for (int kk = 0; kk < 32; ++kk) {
      float4 av = *(const float4*)&As[kk][ty*4];
      float4 bv = *(const float4*)&Bs[kk][tx*4];
      acc[0][0]=fmaf(av.x,bv.x,acc[0][0]); acc[0][1]=fmaf(av.x,bv.y,acc[0][1]);
      acc[0][2]=fmaf(av.x,bv.z,acc[0][2]); acc[0][3]=fmaf(av.x,bv.w,acc[0][3]);
      acc[1][0]=fmaf(av.y,bv.x,acc[1][0]); acc[1][1]=fmaf(av.y,bv.y,acc[1][1]);
      acc[1][2]=fmaf(av.y,bv.z,acc[1][2]); acc[1][3]=fmaf(av.y,bv.w,acc[1][3]);
      acc[2][0]=fmaf(av.z,bv.x,acc[2][0]); acc[2][1]=fmaf(av.z,bv.y,acc[2][1]);
      acc[2][2]=fmaf(av.z,bv.z,acc[2][2]); acc[2][3]=fmaf(av.z,bv.w,acc[2][3]);
      acc[3][0]=fmaf(av.w,bv.x,acc[3][0]); acc[3][1]=fmaf(av.w,bv.y,acc[3][1]);
      acc[3][2]=fmaf(av.w,bv.z,acc[3][2]); acc[3][3]=fmaf(av.w,bv.w,acc[3][3]);
    }
  }
#pragma unroll
  for (int ii = 0; ii < 4; ++ii) {
    *(float4*)&C[(size_t)(m0 + ty*4 + ii) * 8192 + n0 + tx*4] =
        make_float4(acc[ii][0], acc[ii][1], acc[ii][2], acc[ii][3]);
  }
}

// ---------------- encoder LSTM step (ping-pong h) ----------------
// grid 256 blocks (2 h-dims each) x 256 threads
__global__ __launch_bounds__(256) void k_enc_step(
    const float* __restrict__ xprojT,   // [2048][8192]
    const float* __restrict__ Whh,      // [2048][512]
    const int* __restrict__ lens_sorted,
    const float* __restrict__ h_in,
    float* __restrict__ h_out,
    float* __restrict__ c,
    float* __restrict__ hs,             // [64][128][512]
    int t)
{
  __shared__ float hbuf[64][129];
  __shared__ float wbuf[8][128];
  __shared__ float gbuf[4][2][64];
  int tid = threadIdx.x;
  int b = tid & 63;
  int z = tid >> 6;         // 0..3
  int hd_l = z & 1;
  int gp = z >> 1;          // gate pair
  int hd = blockIdx.x * 2 + hd_l;
  int r0 = (2*gp) * 512 + hd;
  int r1 = (2*gp + 1) * 512 + hd;
  float acc0 = xprojT[(size_t)r0 * 8192 + t*64 + b];
  float acc1 = xprojT[(size_t)r1 * 8192 + t*64 + b];
  int w0 = (2*gp)*2 + hd_l;
  int w1 = w0 + 2;
  int kq = tid & 31, bb = tid >> 5;
  int wr = tid >> 5;
  int g = wr >> 1, hl = wr & 1;
  for (int kc = 0; kc < 512; kc += 128) {
    __syncthreads();
#pragma unroll
    for (int ii = 0; ii < 8; ++ii) {
      int br = bb + ii*8;
      float4 v = *(const float4*)&h_in[br*512 + kc + kq*4];
      hbuf[br][kq*4+0]=v.x; hbuf[br][kq*4+1]=v.y; hbuf[br][kq*4+2]=v.z; hbuf[br][kq*4+3]=v.w;
    }
    {
      float4 wv = *(const float4*)&Whh[(size_t)(g*512 + blockIdx.x*2 + hl) * 512 + kc + kq*4];
      wbuf[wr][kq*4+0]=wv.x; wbuf[wr][kq*4+1]=wv.y; wbuf[wr][kq*4+2]=wv.z; wbuf[wr][kq*4+3]=wv.w;
    }
    __syncthreads();
#pragma unroll 8
    for (int kk = 0; kk < 128; ++kk) {
      float hv = hbuf[b][kk];
      acc0 = fmaf(hv, wbuf[w0][kk], acc0);
      acc1 = fmaf(hv, wbuf[w1][kk], acc1);
    }
  }
  gbuf[2*gp][hd_l][b] = acc0;
  gbuf[2*gp+1][hd_l][b] = acc1;
  __syncthreads();
  if (z < 2) {
    int hdg = blockIdx.x*2 + z;
    float gi = gbuf[0][z][b], gf = gbuf[1][z][b], gg = gbuf[2][z][b], go = gbuf[3][z][b];
    float co = c[b*512 + hdg];
    float ho = h_in[b*512 + hdg];
    float si = 1.f/(1.f + expf(-gi));
    float sf = 1.f/(1.f + expf(-gf));
    float so = 1.f/(1.f + expf(-go));
    float cn = fmaf(sf, co, si * tanhf(gg));
    float hn = so * tanhf(cn);
    bool valid = t < lens_sorted[b];
    h_out[b*512 + hdg] = valid ? hn : ho;
    c[b*512 + hdg]     = valid ? cn : co;
    hs[((size_t)b*128 + t)*512 + hdg] = valid ? hn : 0.f;
  }
}

// ---------------- att1 = tanh(hs @ W_a1^T) : [64][128] ----------------
__global__ __launch_bounds__(256) void k_att1(const float* __restrict__ hs,
                                              const float* __restrict__ Wa1,
                                              float* __restrict__ att1) {
  int row = blockIdx.x * 4 + (threadIdx.x >> 6);   // 8192 rows
  int lane = threadIdx.x & 63;
  const float* hp = hs + (size_t)row * 512;
  float4 a0 = *(const float4*)&hp[lane*4];
  float4 a1 = *(const float4*)&hp[256 + lane*4];
  float4 w0 = *(const float4*)&Wa1[lane*4];
  float4 w1 = *(const float4*)&Wa1[256 + lane*4];
  float v = a0.x*w0.x + a0.y*w0.y + a0.z*w0.z + a0.w*w0.w
          + a1.x*w1.x + a1.y*w1.y + a1.z*w1.z + a1.w*w1.w;
#pragma unroll
  for (int m = 1; m < 64; m <<= 1) v += __shfl_xor(v, m, 64);
  if (lane == 0) att1[row] = tanhf(v);
}

// ---------------- decoder attention + ctx (block per batch row) ----------------
__global__ __launch_bounds__(256) void k_dec_attn(
    const float* __restrict__ s_in,
    const float* __restrict__ Wa2,
    const float* __restrict__ att1,
    const int* __restrict__ lens_raw,   // UNSORTED mr_lengths (replicates reference bug)
    const float* __restrict__ hs,
    float* __restrict__ ctx,
    float* __restrict__ A_all,
    int t)
{
  __shared__ float red[256];
  __shared__ float alpha[128];
  int i = blockIdx.x;
  int tid = threadIdx.x;
  float p = s_in[i*512 + tid] * Wa2[tid] + s_in[i*512 + 256 + tid] * Wa2[256 + tid];
  red[tid] = p;
  __syncthreads();
  for (int sft = 128; sft > 0; sft >>= 1) {
    if (tid < sft) red[tid] += red[tid + sft];
    __syncthreads();
  }
  float a2 = tanhf(red[0]);
  __syncthreads();
  float e = -1e30f, ex = 0.f;
  if (tid < 128) {
    e = att1[i*128 + tid] * a2;
    if (tid >= lens_raw[i]) e = -1e9f;
  }
  red[tid] = e;
  __syncthreads();
  for (int sft = 128; sft > 0; sft >>= 1) {
    if (tid < sft) red[tid] = fmaxf(red[tid], red[tid + sft]);
    __syncthreads();
  }
  float M = red[0];
  __syncthreads();
  if (tid < 128) ex = expf(e - M);
  red[tid] = (tid < 128) ? ex : 0.f;
  __syncthreads();
  for (int sft = 128; sft > 0; sft >>= 1) {
    if (tid < sft) red[tid] += red[tid + sft];
    __syncthreads();
  }
  float invL = 1.f / red[0];
  if (tid < 128) alpha[tid] = ex * invL;
  __syncthreads();
#pragma unroll
  for (int hh = 0; hh < 2; ++hh) {
    int h = tid + hh*256;
    float acc = 0.f;
    const float* hp = hs + (size_t)i*128*512 + h;
#pragma unroll 8
    for (int ss = 0; ss < 128; ++ss)
      acc = fmaf(alpha[ss], hp[ss*512], acc);
    ctx[i*512 + h] = acc;
    A_all[((size_t)t*64 + i)*1024 + 512 + h] = acc;
  }
}

// ---------------- d = concat(y, ctx) @ W_s^T : [64][512] ----------------
__global__ __launch_bounds__(256) void k_dec_d(
    const float* __restrict__ emb,
    const int* __restrict__ ref,
    const int* __restrict__ order,
    const float* __restrict__ ctx,
    const float* __restrict__ Ws,      // [512][1024]
    float* __restrict__ dvec,
    int t)
{
  __shared__ float Abuf[64][129];
  __shared__ float Wbuf[4][128];
  __shared__ int tok[64];
  int tid = threadIdx.x;
  if (tid < 64) tok[tid] = ref[order[tid]*48 + t];
  int b = tid & 63, q = tid >> 6;
  int kq = tid & 31, bb = tid >> 5;
  float acc = 0.f;
  for (int kc = 0; kc < 1024; kc += 128) {
    __syncthreads();
    if (kc < 512) {
#pragma unroll
      for (int ii = 0; ii < 8; ++ii) {
        int br = bb + ii*8;
        float4 v = *(const float4*)&emb[(size_t)tok[br]*512 + kc + kq*4];
        Abuf[br][kq*4+0]=v.x; Abuf[br][kq*4+1]=v.y; Abuf[br][kq*4+2]=v.z; Abuf[br][kq*4+3]=v.w;
      }
    } else {
#pragma unroll
      for (int ii = 0; ii < 8; ++ii) {
        int br = bb + ii*8;
        float4 v = *(const float4*)&ctx[br*512 + (kc - 512) + kq*4];
        Abuf[br][kq*4+0]=v.x; Abuf[br][kq*4+1]=v.y; Abuf[br][kq*4+2]=v.z; Abuf[br][kq*4+3]=v.w;
      }
    }
    if (tid < 128) {
      int wr = tid >> 5;   // 0..3
      float4 wv = *(const float4*)&Ws[(size_t)(blockIdx.x*4 + wr)*1024 + kc + kq*4];
      Wbuf[wr][kq*4+0]=wv.x; Wbuf[wr][kq*4+1]=wv.y; Wbuf[wr][kq*4+2]=wv.z; Wbuf[wr][kq*4+3]=wv.w;
    }
    __syncthreads();
#pragma unroll 8
    for (int kk = 0; kk < 128; ++kk)
      acc = fmaf(Abuf[b][kk], Wbuf[q][kk], acc);
  }
  dvec[b*512 + blockIdx.x*4 + q] = acc;
}

// ---------------- decoder LSTM step ----------------
__global__ __launch_bounds__(256) void k_dec_step(
    const float* __restrict__ dvec,
    const float* __restrict__ s_in,
    const float* __restrict__ Wih,
    const float* __restrict__ Whh,
    float* __restrict__ s_out,
    float* __restrict__ m,
    float* __restrict__ A_all,
    int t)
{
  __shared__ float hbuf[64][129];
  __shared__ float wbuf[8][128];
  __shared__ float gbuf[4][2][64];
  int tid = threadIdx.x;
  int b = tid & 63;
  int z = tid >> 6;
  int hd_l = z & 1;
  int gp = z >> 1;
  int w0 = (2*gp)*2 + hd_l;
  int w1 = w0 + 2;
  int kq = tid & 31, bb = tid >> 5;
  int wr = tid >> 5;
  int g = wr >> 1, hl = wr & 1;
  float acc0 = 0.f, acc1 = 0.f;
  for (int pass = 0; pass < 2; ++pass) {
    const float* X = pass ? s_in : dvec;
    const float* W = pass ? Whh : Wih;
    for (int kc = 0; kc < 512; kc += 128) {
      __syncthreads();
#pragma unroll
      for (int ii = 0; ii < 8; ++ii) {
        int br = bb + ii*8;
        float4 v = *(const float4*)&X[br*512 + kc + kq*4];
        hbuf[br][kq*4+0]=v.x; hbuf[br][kq*4+1]=v.y; hbuf[br][kq*4+2]=v.z; hbuf[br][kq*4+3]=v.w;
      }
      {
        float4 wv = *(const float4*)&W[(size_t)(g*512 + blockIdx.x*2 + hl)*512 + kc + kq*4];
        wbuf[wr][kq*4+0]=wv.x; wbuf[wr][kq*4+1]=wv.y; wbuf[wr][kq*4+2]=wv.z; wbuf[wr][kq*4+3]=wv.w;
      }
      __syncthreads();
#pragma unroll 8
      for (int kk = 0; kk < 128; ++kk) {
        float hv = hbuf[b][kk];
        acc0 = fmaf(hv, wbuf[w0][kk], acc0);
        acc1 = fmaf(hv, wbuf[w1][kk], acc1);
      }
    }
  }
  gbuf[2*gp][hd_l][b] = acc0;
  gbuf[2*gp+1][hd_l][b] = acc1;
  __syncthreads();
  if (z < 2) {
    int hdg = blockIdx.x*2 + z;
    float gi = gbuf[0][z][b], gf = gbuf[1][z][b], gg = gbuf[2][z][b], go = gbuf[3][z][b];
    float mo = m[b*512 + hdg];
    float si = 1.f/(1.f + expf(-gi));
    float sf = 1.f/(1.f + expf(-gf));
    float so = 1.f/(1.f + expf(-go));
    float cn = fmaf(sf, mo, si * tanhf(gg));
    float hn = so * tanhf(cn);
    m[b*512 + hdg] = cn;
    s_out[b*512 + hdg] = hn;
    A_all[((size_t)t*64 + b)*1024 + hdg] = hn;
  }
}

// ---------------- logits GEMM: [3072,1024] @ W_y^T -> d_out (desorted rows) ----------------
__global__ __launch_bounds__(256) void k_gemm_logits(
    const float* __restrict__ A,    // A_all [3072][1024]
    const float* __restrict__ Bw,   // W_y [32000][1024]
    const int* __restrict__ order,
    float* __restrict__ out)        // [64][48][32000]
{
  __shared__ float As[32][68];
  __shared__ float Bs[32][68];
  int tid = threadIdx.x;
  int n0 = blockIdx.x * 64;
  int m0 = blockIdx.y * 64;       // = t*64
  int lr = tid >> 2;
  int lk = (tid & 3) * 8;
  const float* Arow = A + (size_t)(m0 + lr) * 1024 + lk;
  const float* Brow = Bw + (size_t)(n0 + lr) * 1024 + lk;
  int tx = tid & 15, ty = tid >> 4;
  float acc[4][4] = {};
  for (int k0 = 0; k0 < 1024; k0 += 32) {
    float4 a0 = *(const float4*)(Arow + k0);
    float4 a1 = *(const float4*)(Arow + k0 + 4);
    float4 b0 = *(const float4*)(Brow + k0);
    float4 b1 = *(const float4*)(Brow + k0 + 4);
    __syncthreads();
    As[lk+0][lr]=a0.x; As[lk+1][lr]=a0.y; As[lk+2][lr]=a0.z; As[lk+3][lr]=a0.w;
    As[lk+4][lr]=a1.x; As[lk+5][lr]=a1.y; As[lk+6][lr]=a1.z; As[lk+7][lr]=a1.w;
    Bs[lk+0][lr]=b0.x; Bs[lk+1][lr]=b0.y; Bs[lk+2][lr]=b0.z; Bs[lk+3][lr]=b0.w;
    Bs[lk+4][lr]=b1.x; Bs[lk+5][lr]=b1.y; Bs[lk+6][lr]=b1.z; Bs[lk+7][lr]=b1.w;
    __syncthreads();
#pragma unroll
    for (int kk = 0; kk < 32; ++kk) {
      float4 av = *(const float4*)&As[kk][ty*4];
      float4 bv = *(const float4*)&Bs[kk][tx*4];
      acc[0][0]=fmaf(av.x,bv.x,acc[0][0]); acc[0][1]=fmaf(av.x,bv.y,acc[0][1]);
      acc[0][2]=fmaf(av.x,bv.z,acc[0][2]); acc[0][3]=fmaf(av.x,bv.w,acc[0][3]);
      acc[1][0]=fmaf(av.y,bv.x,acc[1][0]); acc[1][1]=fmaf(av.y,bv.y,acc[1][1]);
      acc[1][2]=fmaf(av.y,bv.z,acc[1][2]); acc[1][3]=fmaf(av.y,bv.w,acc[1][3]);
      acc[2][0]=fmaf(av.z,bv.x,acc[2][0]); acc[2][1]=fmaf(av.z,bv.y,acc[2][1]);
      acc[2][2]=fmaf(av.z,bv.z,acc[2][2]); acc[2][3]=fmaf(av.z,bv.w,acc[2][3]);
      acc[3][0]=fmaf(av.w,bv.x,acc[3][0]); acc[3][1]=fmaf(av.w,bv.y,acc[3][1]);
      acc[3][2]=fmaf(av.w,bv.z,acc[3][2]); acc[3][3]=fmaf(av.w,bv.w,acc[3][3]);
    }
  }
  int tt = blockIdx.y;
#pragma unroll
  for (int ii = 0; ii < 4; ++ii) {
    int i = ty*4 + ii;    // sorted batch index within this t
    size_t orow = ((size_t)order[i]*48 + tt) * 32000;
    *(float4*)&out[orow + n0 + tx*4] =
        make_float4(acc[ii][0], acc[ii][1], acc[ii][2], acc[ii][3]);
  }
}

// ---------------- in-place row softmax over V=32000 ----------------
__global__ __launch_bounds__(256) void k_softmax(float* __restrict__ out) {
  size_t base = (size_t)blockIdx.x * 32000;
  int tid = threadIdx.x;
  float mx = -1e30f, l = 0.f;
  for (int j = tid; j < 32000; j += 256) {
    float x = out[base + j];
    float mn = fmaxf(mx, x);
    l = l * expf(mx - mn) + expf(x - mn);
    mx = mn;
  }
  __shared__ float sm[256], sl[256];
  sm[tid] = mx; sl[tid] = l;
  __syncthreads();
  for (int sft = 128; sft > 0; sft >>= 1) {
    if (tid < sft) {
      float m2 = sm[tid+sft], l2 = sl[tid+sft];
      float M = fmaxf(sm[tid], m2);
      sl[tid] = sl[tid]*expf(sm[tid]-M) + l2*expf(m2-M);
      sm[tid] = M;
    }
    __syncthreads();
  }
  float M = sm[0], inv = 1.f / sl[0];
  for (int j = tid; j < 32000; j += 256) {
    out[base + j] = expf(out[base + j] - M) * inv;
  }
}

extern "C" void kernel_launch(void* const* d_in, const int* in_sizes, int n_in,
                              void* d_out, int out_size, void* d_ws, size_t ws_size,
                              hipStream_t stream) {
  const int*   mr    = (const int*)d_in[0];
  const int*   ref   = (const int*)d_in[1];
  const int*   lens  = (const int*)d_in[2];
  const float* emb   = (const float*)d_in[3];
  const float* Wih_e = (const float*)d_in[4];
  const float* Whh_e = (const float*)d_in[5];
  const float* Wih_d = (const float*)d_in[6];
  const float* Whh_d = (const float*)d_in[7];
  const float* Wy    = (const float*)d_in[8];
  const float* Ws    = (const float*)d_in[9];
  const float* Wa1   = (const float*)d_in[10];
  const float* Wa2   = (const float*)d_in[11];
  float* out = (float*)d_out;

  float* wsf = (float*)d_ws;
  int* order       = (int*)wsf;              // 64
  int* lens_sorted = (int*)(wsf + 64);       // 64
  int* rowtok      = (int*)(wsf + 128);      // 8192
  float* xprojT = wsf + 8320;                          // 2048*8192
  float* h0     = xprojT + (size_t)2048*8192;          // 64*512
  float* h1     = h0 + 64*512;
  float* cbuf   = h1 + 64*512;
  float* hs     = cbuf + 64*512;                       // 64*128*512
  float* att1   = hs + (size_t)64*128*512;             // 8192
  float* ctx    = att1 + 8192;                         // 64*512
  float* dvec   = ctx + 64*512;                        // 64*512
  float* A_all  = dvec + 64*512;                       // 3072*1024

  hipMemsetAsync(h0, 0, 64*512*sizeof(float), stream);
  hipMemsetAsync(cbuf, 0, 64*512*sizeof(float), stream);

  k_sort<<<1, 64, 0, stream>>>(lens, order, lens_sorted);
  k_rowtok<<<32, 256, 0, stream>>>(mr, order, rowtok);
  k_gemm_xproj<<<dim3(128, 32), 256, 0, stream>>>(Wih_e, emb, rowtok, xprojT);

  float* hping[2] = {h0, h1};
  for (int t = 0; t < 128; ++t) {
    k_enc_step<<<256, 256, 0, stream>>>(xprojT, Whh_e, lens_sorted,
                                        hping[t & 1], hping[(t+1) & 1], cbuf, hs, t);
  }
  k_att1<<<2048, 256, 0, stream>>>(hs, Wa1, att1);

  for (int t = 0; t < 48; ++t) {
    k_dec_attn<<<64, 256, 0, stream>>>(hping[t & 1], Wa2, att1, lens, hs, ctx, A_all, t);
    k_dec_d<<<128, 256, 0, stream>>>(emb, ref, order, ctx, Ws, dvec, t);
    k_dec_step<<<256, 256, 0, stream>>>(dvec, hping[t & 1], Wih_d, Whh_d,
                                        hping[(t+1) & 1], cbuf, A_all, t);
  }

  k_gemm_logits<<<dim3(500, 48), 256, 0, stream>>>(A_all, Wy, order, out);
  k_softmax<<<3072, 256, 0, stream>>>(out);
}

// Round 2
// 5886.255 us; speedup vs baseline: 1.4475x; 1.4475x over previous
//
#include <hip/hip_runtime.h>
#include <cstddef>
#include <cstdint>

// Problem constants
// V=32000, H=512, E=512, B=64, S=128, T=48
// Inputs: 0:mr[64,128] i32, 1:ref[64,48] i32, 2:mr_lengths[64] i32, 3:emb[32000,512] f32,
// 4:W_ih_enc[2048,512], 5:W_hh_enc[2048,512], 6:W_ih_dec[2048,512], 7:W_hh_dec[2048,512],
// 8:W_y[32000,1024], 9:W_s[512,1024], 10:W_a1[1,512], 11:W_a2[1,512]
// Output: [64,48,32000] f32 (softmax probs)

typedef __bf16 bf16x8 __attribute__((ext_vector_type(8)));
typedef float f32x4 __attribute__((ext_vector_type(4)));

__device__ inline unsigned short f2bf(float f) {
  unsigned int u = __float_as_uint(f);
  unsigned int r = (u + 0x7FFFu + ((u >> 16) & 1u)) >> 16;   // RNE
  return (unsigned short)r;
}

__device__ inline void gload_lds16(const void* g, void* l) {
  __builtin_amdgcn_global_load_lds((const __attribute__((address_space(1))) void*)g,
                                   (__attribute__((address_space(3))) void*)l, 16, 0, 0);
}

// ---------------- sort: order = stable argsort(-lens) ----------------
__global__ __launch_bounds__(64) void k_sort(const int* __restrict__ lens,
                                             int* __restrict__ order,
                                             int* __restrict__ lens_sorted) {
  __shared__ int L[64];
  int i = threadIdx.x;
  L[i] = lens[i];
  __syncthreads();
  int li = L[i];
  int rank = 0;
  for (int j = 0; j < 64; ++j) {
    int lj = L[j];
    if (lj > li || (lj == li && j < i)) ++rank;
  }
  order[rank] = i;
  lens_sorted[rank] = li;
}

// ---------------- token index per encoder-GEMM row ----------------
__global__ __launch_bounds__(256) void k_rowtok(const int* __restrict__ mr,
                                                const int* __restrict__ order,
                                                int* __restrict__ rowtok) {
  int r = blockIdx.x * 256 + threadIdx.x;   // 8192 rows, row = s*64 + i(sorted)
  int s = r >> 6, i = r & 63;
  rowtok[r] = mr[order[i] * 128 + s];
}

// ---------------- fp32 -> bf16 conversion (grid-stride, float4 in, ushort4 out) ---
__global__ __launch_bounds__(256) void k_cvt_bf16(const float* __restrict__ src,
                                                  unsigned short* __restrict__ dst,
                                                  int n4) {
  int i = blockIdx.x * 256 + threadIdx.x;
  int stride = gridDim.x * 256;
  for (; i < n4; i += stride) {
    float4 v = ((const float4*)src)[i];
    ushort4 o;
    o.x = f2bf(v.x); o.y = f2bf(v.y); o.z = f2bf(v.z); o.w = f2bf(v.w);
    ((ushort4*)dst)[i] = o;
  }
}

// ---------------- xprojT = W_ih_enc @ x_s^T : [2048][8192] ----------------
__global__ __launch_bounds__(256) void k_gemm_xproj(
    const float* __restrict__ A,      // W_ih_enc [2048][512]
    const float* __restrict__ emb,    // [V][512]
    const int* __restrict__ rowtok,   // [8192]
    float* __restrict__ C)            // [2048][8192]
{
  __shared__ float As[32][68];
  __shared__ float Bs[32][68];
  int tid = threadIdx.x;
  int n0 = blockIdx.x * 64;
  int m0 = blockIdx.y * 64;
  int lr = tid >> 2;            // 0..63
  int lk = (tid & 3) * 8;       // 0,8,16,24
  const float* Arow = A + (size_t)(m0 + lr) * 512 + lk;
  const float* Brow = emb + (size_t)rowtok[n0 + lr] * 512 + lk;
  int tx = tid & 15, ty = tid >> 4;
  float acc[4][4] = {};
  for (int k0 = 0; k0 < 512; k0 += 32) {
    float4 a0 = *(const float4*)(Arow + k0);
    float4 a1 = *(const float4*)(Arow + k0 + 4);
    float4 b0 = *(const float4*)(Brow + k0);
    float4 b1 = *(const float4*)(Brow + k0 + 4);
    __syncthreads();
    As[lk+0][lr]=a0.x; As[lk+1][lr]=a0.y; As[lk+2][lr]=a0.z; As[lk+3][lr]=a0.w;
    As[lk+4][lr]=a1.x; As[lk+5][lr]=a1.y; As[lk+6][lr]=a1.z; As[lk+7][lr]=a1.w;
    Bs[lk+0][lr]=b0.x; Bs[lk+1][lr]=b0.y; Bs[lk+2][lr]=b0.z; Bs[lk+3][lr]=b0.w;
    Bs[lk+4][lr]=b1.x; Bs[lk+5][lr]=b1.y; Bs[lk+6][lr]=b1.z; Bs[lk+7][lr]=b1.w;
    __syncthreads();
#pragma unroll
    for (int kk = 0; kk < 32; ++kk) {
      float4 av = *(const float4*)&As[kk][ty*4];
      float4 bv = *(const float4*)&Bs[kk][tx*4];
      acc[0][0]=fmaf(av.x,bv.x,acc[0][0]); acc[0][1]=fmaf(av.x,bv.y,acc[0][1]);
      acc[0][2]=fmaf(av.x,bv.z,acc[0][2]); acc[0][3]=fmaf(av.x,bv.w,acc[0][3]);
      acc[1][0]=fmaf(av.y,bv.x,acc[1][0]); acc[1][1]=fmaf(av.y,bv.y,acc[1][1]);
      acc[1][2]=fmaf(av.y,bv.z,acc[1][2]); acc[1][3]=fmaf(av.y,bv.w,acc[1][3]);
      acc[2][0]=fmaf(av.z,bv.x,acc[2][0]); acc[2][1]=fmaf(av.z,bv.y,acc[2][1]);
      acc[2][2]=fmaf(av.z,bv.z,acc[2][2]); acc[2][3]=fmaf(av.z,bv.w,acc[2][3]);
      acc[3][0]=fmaf(av.w,bv.x,acc[3][0]); acc[3][1]=fmaf(av.w,bv.y,acc[3][1]);
      acc[3][2]=fmaf(av.w,bv.z,acc[3][2]); acc[3][3]=fmaf(av.w,bv.w,acc[3][3]);
    }
  }
#pragma unroll
  for (int ii = 0; ii < 4; ++ii) {
    *(float4*)&C[(size_t)(m0 + ty*4 + ii) * 8192 + n0 + tx*4] =
        make_float4(acc[ii][0], acc[ii][1], acc[ii][2], acc[ii][3]);
  }
}

// ---------------- encoder LSTM step (ping-pong h) ----------------
__global__ __launch_bounds__(256) void k_enc_step(
    const float* __restrict__ xprojT,   // [2048][8192]
    const float* __restrict__ Whh,      // [2048][512]
    const int* __restrict__ lens_sorted,
    const float* __restrict__ h_in,
    float* __restrict__ h_out,
    float* __restrict__ c,
    float* __restrict__ hs,             // [64][128][512]
    int t)
{
  __shared__ float hbuf[64][129];
  __shared__ float wbuf[8][128];
  __shared__ float gbuf[4][2][64];
  int tid = threadIdx.x;
  int b = tid & 63;
  int z = tid >> 6;         // 0..3
  int hd_l = z & 1;
  int gp = z >> 1;          // gate pair
  int hd = blockIdx.x * 2 + hd_l;
  int r0 = (2*gp) * 512 + hd;
  int r1 = (2*gp + 1) * 512 + hd;
  float acc0 = xprojT[(size_t)r0 * 8192 + t*64 + b];
  float acc1 = xprojT[(size_t)r1 * 8192 + t*64 + b];
  int w0 = (2*gp)*2 + hd_l;
  int w1 = w0 + 2;
  int kq = tid & 31, bb = tid >> 5;
  int wr = tid >> 5;
  int g = wr >> 1, hl = wr & 1;
  for (int kc = 0; kc < 512; kc += 128) {
    __syncthreads();
#pragma unroll
    for (int ii = 0; ii < 8; ++ii) {
      int br = bb + ii*8;
      float4 v = *(const float4*)&h_in[br*512 + kc + kq*4];
      hbuf[br][kq*4+0]=v.x; hbuf[br][kq*4+1]=v.y; hbuf[br][kq*4+2]=v.z; hbuf[br][kq*4+3]=v.w;
    }
    {
      float4 wv = *(const float4*)&Whh[(size_t)(g*512 + blockIdx.x*2 + hl) * 512 + kc + kq*4];
      wbuf[wr][kq*4+0]=wv.x; wbuf[wr][kq*4+1]=wv.y; wbuf[wr][kq*4+2]=wv.z; wbuf[wr][kq*4+3]=wv.w;
    }
    __syncthreads();
#pragma unroll 8
    for (int kk = 0; kk < 128; ++kk) {
      float hv = hbuf[b][kk];
      acc0 = fmaf(hv, wbuf[w0][kk], acc0);
      acc1 = fmaf(hv, wbuf[w1][kk], acc1);
    }
  }
  gbuf[2*gp][hd_l][b] = acc0;
  gbuf[2*gp+1][hd_l][b] = acc1;
  __syncthreads();
  if (z < 2) {
    int hdg = blockIdx.x*2 + z;
    float gi = gbuf[0][z][b], gf = gbuf[1][z][b], gg = gbuf[2][z][b], go = gbuf[3][z][b];
    float co = c[b*512 + hdg];
    float ho = h_in[b*512 + hdg];
    float si = 1.f/(1.f + expf(-gi));
    float sf = 1.f/(1.f + expf(-gf));
    float so = 1.f/(1.f + expf(-go));
    float cn = fmaf(sf, co, si * tanhf(gg));
    float hn = so * tanhf(cn);
    bool valid = t < lens_sorted[b];
    h_out[b*512 + hdg] = valid ? hn : ho;
    c[b*512 + hdg]     = valid ? cn : co;
    hs[((size_t)b*128 + t)*512 + hdg] = valid ? hn : 0.f;
  }
}

// ---------------- att1 = tanh(hs @ W_a1^T) : [64][128] ----------------
__global__ __launch_bounds__(256) void k_att1(const float* __restrict__ hs,
                                              const float* __restrict__ Wa1,
                                              float* __restrict__ att1) {
  int row = blockIdx.x * 4 + (threadIdx.x >> 6);   // 8192 rows
  int lane = threadIdx.x & 63;
  const float* hp = hs + (size_t)row * 512;
  float4 a0 = *(const float4*)&hp[lane*4];
  float4 a1 = *(const float4*)&hp[256 + lane*4];
  float4 w0 = *(const float4*)&Wa1[lane*4];
  float4 w1 = *(const float4*)&Wa1[256 + lane*4];
  float v = a0.x*w0.x + a0.y*w0.y + a0.z*w0.z + a0.w*w0.w
          + a1.x*w1.x + a1.y*w1.y + a1.z*w1.z + a1.w*w1.w;
#pragma unroll
  for (int m = 1; m < 64; m <<= 1) v += __shfl_xor(v, m, 64);
  if (lane == 0) att1[row] = tanhf(v);
}

// ---------------- decoder attention + ctx (block per batch row) ----------------
__global__ __launch_bounds__(256) void k_dec_attn(
    const float* __restrict__ s_in,
    const float* __restrict__ Wa2,
    const float* __restrict__ att1,
    const int* __restrict__ lens_raw,   // UNSORTED mr_lengths (replicates reference bug)
    const float* __restrict__ hs,
    float* __restrict__ ctx,
    unsigned short* __restrict__ A_bf,  // bf16 [48*64][1024]
    int t)
{
  __shared__ float red[256];
  __shared__ float alpha[128];
  int i = blockIdx.x;
  int tid = threadIdx.x;
  float p = s_in[i*512 + tid] * Wa2[tid] + s_in[i*512 + 256 + tid] * Wa2[256 + tid];
  red[tid] = p;
  __syncthreads();
  for (int sft = 128; sft > 0; sft >>= 1) {
    if (tid < sft) red[tid] += red[tid + sft];
    __syncthreads();
  }
  float a2 = tanhf(red[0]);
  __syncthreads();
  float e = -1e30f, ex = 0.f;
  if (tid < 128) {
    e = att1[i*128 + tid] * a2;
    if (tid >= lens_raw[i]) e = -1e9f;
  }
  red[tid] = e;
  __syncthreads();
  for (int sft = 128; sft > 0; sft >>= 1) {
    if (tid < sft) red[tid] = fmaxf(red[tid], red[tid + sft]);
    __syncthreads();
  }
  float M = red[0];
  __syncthreads();
  if (tid < 128) ex = expf(e - M);
  red[tid] = (tid < 128) ? ex : 0.f;
  __syncthreads();
  for (int sft = 128; sft > 0; sft >>= 1) {
    if (tid < sft) red[tid] += red[tid + sft];
    __syncthreads();
  }
  float invL = 1.f / red[0];
  if (tid < 128) alpha[tid] = ex * invL;
  __syncthreads();
#pragma unroll
  for (int hh = 0; hh < 2; ++hh) {
    int h = tid + hh*256;
    float acc = 0.f;
    const float* hp = hs + (size_t)i*128*512 + h;
#pragma unroll 8
    for (int ss = 0; ss < 128; ++ss)
      acc = fmaf(alpha[ss], hp[ss*512], acc);
    ctx[i*512 + h] = acc;
    A_bf[((size_t)t*64 + i)*1024 + 512 + h] = f2bf(acc);
  }
}

// ---------------- d = concat(y, ctx) @ W_s^T : [64][512] ----------------
__global__ __launch_bounds__(256) void k_dec_d(
    const float* __restrict__ emb,
    const int* __restrict__ ref,
    const int* __restrict__ order,
    const float* __restrict__ ctx,
    const float* __restrict__ Ws,      // [512][1024]
    float* __restrict__ dvec,
    int t)
{
  __shared__ float Abuf[64][129];
  __shared__ float Wbuf[4][128];
  __shared__ int tok[64];
  int tid = threadIdx.x;
  if (tid < 64) tok[tid] = ref[order[tid]*48 + t];
  int b = tid & 63, q = tid >> 6;
  int kq = tid & 31, bb = tid >> 5;
  float acc = 0.f;
  for (int kc = 0; kc < 1024; kc += 128) {
    __syncthreads();
    if (kc < 512) {
#pragma unroll
      for (int ii = 0; ii < 8; ++ii) {
        int br = bb + ii*8;
        float4 v = *(const float4*)&emb[(size_t)tok[br]*512 + kc + kq*4];
        Abuf[br][kq*4+0]=v.x; Abuf[br][kq*4+1]=v.y; Abuf[br][kq*4+2]=v.z; Abuf[br][kq*4+3]=v.w;
      }
    } else {
#pragma unroll
      for (int ii = 0; ii < 8; ++ii) {
        int br = bb + ii*8;
        float4 v = *(const float4*)&ctx[br*512 + (kc - 512) + kq*4];
        Abuf[br][kq*4+0]=v.x; Abuf[br][kq*4+1]=v.y; Abuf[br][kq*4+2]=v.z; Abuf[br][kq*4+3]=v.w;
      }
    }
    if (tid < 128) {
      int wr = tid >> 5;   // 0..3
      float4 wv = *(const float4*)&Ws[(size_t)(blockIdx.x*4 + wr)*1024 + kc + kq*4];
      Wbuf[wr][kq*4+0]=wv.x; Wbuf[wr][kq*4+1]=wv.y; Wbuf[wr][kq*4+2]=wv.z; Wbuf[wr][kq*4+3]=wv.w;
    }
    __syncthreads();
#pragma unroll 8
    for (int kk = 0; kk < 128; ++kk)
      acc = fmaf(Abuf[b][kk], Wbuf[q][kk], acc);
  }
  dvec[b*512 + blockIdx.x*4 + q] = acc;
}

// ---------------- decoder LSTM step ----------------
__global__ __launch_bounds__(256) void k_dec_step(
    const float* __restrict__ dvec,
    const float* __restrict__ s_in,
    const float* __restrict__ Wih,
    const float* __restrict__ Whh,
    float* __restrict__ s_out,
    float* __restrict__ m,
    unsigned short* __restrict__ A_bf,
    int t)
{
  __shared__ float hbuf[64][129];
  __shared__ float wbuf[8][128];
  __shared__ float gbuf[4][2][64];
  int tid = threadIdx.x;
  int b = tid & 63;
  int z = tid >> 6;
  int hd_l = z & 1;
  int gp = z >> 1;
  int w0 = (2*gp)*2 + hd_l;
  int w1 = w0 + 2;
  int kq = tid & 31, bb = tid >> 5;
  int wr = tid >> 5;
  int g = wr >> 1, hl = wr & 1;
  float acc0 = 0.f, acc1 = 0.f;
  for (int pass = 0; pass < 2; ++pass) {
    const float* X = pass ? s_in : dvec;
    const float* W = pass ? Whh : Wih;
    for (int kc = 0; kc < 512; kc += 128) {
      __syncthreads();
#pragma unroll
      for (int ii = 0; ii < 8; ++ii) {
        int br = bb + ii*8;
        float4 v = *(const float4*)&X[br*512 + kc + kq*4];
        hbuf[br][kq*4+0]=v.x; hbuf[br][kq*4+1]=v.y; hbuf[br][kq*4+2]=v.z; hbuf[br][kq*4+3]=v.w;
      }
      {
        float4 wv = *(const float4*)&W[(size_t)(g*512 + blockIdx.x*2 + hl)*512 + kc + kq*4];
        wbuf[wr][kq*4+0]=wv.x; wbuf[wr][kq*4+1]=wv.y; wbuf[wr][kq*4+2]=wv.z; wbuf[wr][kq*4+3]=wv.w;
      }
      __syncthreads();
#pragma unroll 8
      for (int kk = 0; kk < 128; ++kk) {
        float hv = hbuf[b][kk];
        acc0 = fmaf(hv, wbuf[w0][kk], acc0);
        acc1 = fmaf(hv, wbuf[w1][kk], acc1);
      }
    }
  }
  gbuf[2*gp][hd_l][b] = acc0;
  gbuf[2*gp+1][hd_l][b] = acc1;
  __syncthreads();
  if (z < 2) {
    int hdg = blockIdx.x*2 + z;
    float gi = gbuf[0][z][b], gf = gbuf[1][z][b], gg = gbuf[2][z][b], go = gbuf[3][z][b];
    float mo = m[b*512 + hdg];
    float si = 1.f/(1.f + expf(-gi));
    float sf = 1.f/(1.f + expf(-gf));
    float so = 1.f/(1.f + expf(-go));
    float cn = fmaf(sf, mo, si * tanhf(gg));
    float hn = so * tanhf(cn);
    m[b*512 + hdg] = cn;
    s_out[b*512 + hdg] = hn;
    A_bf[((size_t)t*64 + b)*1024 + hdg] = f2bf(hn);
  }
}

// ---------------- logits GEMM (bf16 MFMA): [3072,1024] @ W_y^T -> out -----------
// m97-style: 128x128 tile, BK=32, global_load_lds w=16, 16x16x32 MFMA, 4 waves
__global__ __launch_bounds__(256) void k_gemm_logits_bf16(
    const unsigned short* __restrict__ A,    // A_all bf16 [3072][1024]
    const unsigned short* __restrict__ Bw,   // W_y bf16 [32000][1024]
    const int* __restrict__ order,
    float* __restrict__ out)                 // [64][48][32000]
{
  __shared__ unsigned short As[128*32];
  __shared__ unsigned short Bs[128*32];
  __shared__ int ord_s[64];
  int tid = threadIdx.x;
  if (tid < 64) ord_s[tid] = order[tid];
  int m0 = blockIdx.x * 128;      // 24 M-tiles
  int n0 = blockIdx.y * 128;      // 250 N-tiles
  int wave = tid >> 6, lane = tid & 63;
  // staging: wave-uniform LDS base + lane*16B (global_load_lds semantics)
  int srow = wave*16 + (lane >> 2);
  int skel = (lane & 3) * 8;
  const unsigned short* gA = A  + (size_t)(m0 + srow) * 1024 + skel;
  const unsigned short* gB = Bw + (size_t)(n0 + srow) * 1024 + skel;
  unsigned short* lA = &As[wave * 512];
  unsigned short* lB = &Bs[wave * 512];
  int wrow = (wave >> 1) * 64, wcol = (wave & 1) * 64;
  int lr = lane & 15, lq = lane >> 4;
  f32x4 acc[4][4];
#pragma unroll
  for (int i = 0; i < 4; ++i)
#pragma unroll
    for (int j = 0; j < 4; ++j) acc[i][j] = (f32x4){0.f, 0.f, 0.f, 0.f};

  for (int k0 = 0; k0 < 1024; k0 += 32) {
    gload_lds16(gA + k0,             lA);          // rows 0..63 of A-tile
    gload_lds16(gA + k0 + 64*1024,   lA + 2048);   // rows 64..127
    gload_lds16(gB + k0,             lB);
    gload_lds16(gB + k0 + 64*1024,   lB + 2048);
    __syncthreads();
    bf16x8 af[4], bf[4];
#pragma unroll
    for (int i = 0; i < 4; ++i) {
      af[i] = *(const bf16x8*)&As[(wrow + i*16 + lr)*32 + lq*8];
      bf[i] = *(const bf16x8*)&Bs[(wcol + i*16 + lr)*32 + lq*8];
    }
#pragma unroll
    for (int i = 0; i < 4; ++i)
#pragma unroll
      for (int j = 0; j < 4; ++j)
        acc[i][j] = __builtin_amdgcn_mfma_f32_16x16x32_bf16(af[i], bf[j], acc[i][j], 0, 0, 0);
    __syncthreads();
  }
  // epilogue: C/D layout col=lane&15, row=(lane>>4)*4+reg ; desort rows into out
#pragma unroll
  for (int i = 0; i < 4; ++i) {
    int gmBase = m0 + wrow + i*16 + lq*4;
#pragma unroll
    for (int j = 0; j < 4; ++j) {
      int gn = n0 + wcol + j*16 + lr;
#pragma unroll
      for (int r = 0; r < 4; ++r) {
        int gm = gmBase + r;
        size_t orow = (size_t)ord_s[gm & 63] * 48 + (gm >> 6);
        out[orow * 32000 + gn] = acc[i][j][r];
      }
    }
  }
}

// ---------------- in-place row softmax over V=32000 ----------------
__global__ __launch_bounds__(256) void k_softmax(float* __restrict__ out) {
  size_t base = (size_t)blockIdx.x * 32000;
  int tid = threadIdx.x;
  float mx = -1e30f, l = 0.f;
  for (int j = tid; j < 32000; j += 256) {
    float x = out[base + j];
    float mn = fmaxf(mx, x);
    l = l * expf(mx - mn) + expf(x - mn);
    mx = mn;
  }
  __shared__ float sm[256], sl[256];
  sm[tid] = mx; sl[tid] = l;
  __syncthreads();
  for (int sft = 128; sft > 0; sft >>= 1) {
    if (tid < sft) {
      float m2 = sm[tid+sft], l2 = sl[tid+sft];
      float M = fmaxf(sm[tid], m2);
      sl[tid] = sl[tid]*expf(sm[tid]-M) + l2*expf(m2-M);
      sm[tid] = M;
    }
    __syncthreads();
  }
  float M = sm[0], inv = 1.f / sl[0];
  for (int j = tid; j < 32000; j += 256) {
    out[base + j] = expf(out[base + j] - M) * inv;
  }
}

extern "C" void kernel_launch(void* const* d_in, const int* in_sizes, int n_in,
                              void* d_out, int out_size, void* d_ws, size_t ws_size,
                              hipStream_t stream) {
  const int*   mr    = (const int*)d_in[0];
  const int*   ref   = (const int*)d_in[1];
  const int*   lens  = (const int*)d_in[2];
  const float* emb   = (const float*)d_in[3];
  const float* Wih_e = (const float*)d_in[4];
  const float* Whh_e = (const float*)d_in[5];
  const float* Wih_d = (const float*)d_in[6];
  const float* Whh_d = (const float*)d_in[7];
  const float* Wy    = (const float*)d_in[8];
  const float* Ws    = (const float*)d_in[9];
  const float* Wa1   = (const float*)d_in[10];
  const float* Wa2   = (const float*)d_in[11];
  float* out = (float*)d_out;

  float* wsf = (float*)d_ws;
  int* order       = (int*)wsf;              // 64
  int* lens_sorted = (int*)(wsf + 64);       // 64
  int* rowtok      = (int*)(wsf + 128);      // 8192
  float* xprojT = wsf + 8320;                          // 2048*8192
  float* h0     = xprojT + (size_t)2048*8192;          // 64*512
  float* h1     = h0 + 64*512;
  float* cbuf   = h1 + 64*512;
  float* hs     = cbuf + 64*512;                       // 64*128*512
  float* att1   = hs + (size_t)64*128*512;             // 8192
  float* ctx    = att1 + 8192;                         // 64*512
  float* dvec   = ctx + 64*512;                        // 64*512
  unsigned short* A_bf  = (unsigned short*)(dvec + 64*512);      // 3072*1024 bf16
  unsigned short* Wy_bf = A_bf + (size_t)3072*1024;              // 32000*1024 bf16

  hipMemsetAsync(h0, 0, 64*512*sizeof(float), stream);
  hipMemsetAsync(cbuf, 0, 64*512*sizeof(float), stream);

  k_sort<<<1, 64, 0, stream>>>(lens, order, lens_sorted);
  k_rowtok<<<32, 256, 0, stream>>>(mr, order, rowtok);
  k_cvt_bf16<<<2048, 256, 0, stream>>>(Wy, Wy_bf, 32000*1024/4);
  k_gemm_xproj<<<dim3(128, 32), 256, 0, stream>>>(Wih_e, emb, rowtok, xprojT);

  float* hping[2] = {h0, h1};
  for (int t = 0; t < 128; ++t) {
    k_enc_step<<<256, 256, 0, stream>>>(xprojT, Whh_e, lens_sorted,
                                        hping[t & 1], hping[(t+1) & 1], cbuf, hs, t);
  }
  k_att1<<<2048, 256, 0, stream>>>(hs, Wa1, att1);

  for (int t = 0; t < 48; ++t) {
    k_dec_attn<<<64, 256, 0, stream>>>(hping[t & 1], Wa2, att1, lens, hs, ctx, A_bf, t);
    k_dec_d<<<128, 256, 0, stream>>>(emb, ref, order, ctx, Ws, dvec, t);
    k_dec_step<<<256, 256, 0, stream>>>(dvec, hping[t & 1], Wih_d, Whh_d,
                                        hping[(t+1) & 1], cbuf, A_bf, t);
  }

  k_gemm_logits_bf16<<<dim3(24, 250), 256, 0, stream>>>(A_bf, Wy_bf, order, out);
  k_softmax<<<3072, 256, 0, stream>>>(out);
}